// Round 11
// baseline (527.336 us; speedup 1.0000x reference)
//
#include <hip/hip_runtime.h>
#include <hip/hip_fp8.h>
#include <cstdio>
#include <cstdint>

#define K_DIM 4096
#define N_DIM 4096
#define BKB 64                 // K-bytes per tile step
#define NT (K_DIM / BKB)       // 64 K-tiles

typedef int v4i __attribute__((ext_vector_type(4)));
typedef int v8i __attribute__((ext_vector_type(8)));
typedef float v16f __attribute__((ext_vector_type(16)));

// ---------------------------------------------------------------- amax ------
__global__ void amax_kernel(const float4* __restrict__ x, int n4,
                            unsigned* __restrict__ out) {
  int i = blockIdx.x * blockDim.x + threadIdx.x;
  int stride = gridDim.x * blockDim.x;
  float m = 0.f;
  for (; i < n4; i += stride) {
    float4 v = x[i];
    m = fmaxf(m, fmaxf(fmaxf(fabsf(v.x), fabsf(v.y)),
                       fmaxf(fabsf(v.z), fabsf(v.w))));
  }
#pragma unroll
  for (int off = 32; off > 0; off >>= 1)
    m = fmaxf(m, __shfl_down(m, off, 64));
  __shared__ float wred[4];
  int lane = threadIdx.x & 63, wid = threadIdx.x >> 6;
  if (lane == 0) wred[wid] = m;
  __syncthreads();
  if (threadIdx.x == 0) {
    m = fmaxf(fmaxf(wred[0], wred[1]), fmaxf(wred[2], wred[3]));
    atomicMax(out, __float_as_uint(m));  // bit-compare valid: m >= 0
  }
}

__device__ __forceinline__ float load_scale(const unsigned* p) {
  return fmaxf(__uint_as_float(*p) / 448.0f, 1e-12f);
}

__device__ __forceinline__ unsigned f2fp8(float v) {
  return (unsigned)__hip_cvt_float_to_fp8(v, __HIP_SATFINITE, __HIP_E4M3);
}

__device__ __forceinline__ unsigned pack4(float4 v, float s) {
  return f2fp8(v.x / s) | (f2fp8(v.y / s) << 8) |
         (f2fp8(v.z / s) << 16) | (f2fp8(v.w / s) << 24);
}

// ---------------------------- quantize A -> MFMA-fragment-blocked layout ----
// x: [R][K] fp32 -> Aq chunks of 2048B: chunk (pg, k64), pg = 32-row group,
// lane l = kh*32+r5 holds A[pg*32+r5][k64*64 + kh*32 .. +31].
// One thread per 32B output: reads 128B contiguous, writes 32B coalesced.
__global__ void quant1_kernel(const float* __restrict__ x,
                              unsigned char* __restrict__ q,
                              const unsigned* __restrict__ amax_bits) {
  float s = load_scale(amax_bits);
  int tid = blockIdx.x * blockDim.x + threadIdx.x;   // one per 32B chunk-lane
  int lane = tid & 63;
  int c = tid >> 6;          // chunk id = pg*64 + k64
  int k64 = c & 63;
  int pg = c >> 6;           // 32-row group, 0..511
  int row = pg * 32 + (lane & 31);
  int col = k64 * 64 + (lane >> 5) * 32;
  const float4* src = (const float4*)(x + (size_t)row * K_DIM + col);
  uint4 o0, o1;
  o0.x = pack4(src[0], s); o0.y = pack4(src[1], s);
  o0.z = pack4(src[2], s); o0.w = pack4(src[3], s);
  o1.x = pack4(src[4], s); o1.y = pack4(src[5], s);
  o1.z = pack4(src[6], s); o1.w = pack4(src[7], s);
  uint4* dst = (uint4*)(q + (size_t)tid * 32);
  dst[0] = o0; dst[1] = o1;
}

// ---------------------------- quantize B -> MFMA-fragment-blocked layout ----
// x: [K][N] fp32 -> Bq[n32][k64][lane][32B]: lane l = kh*32+r5 holds
// Bt[n32*32+r5][k64*64 + kh*32 .. +31] (Bt = x transposed).
__global__ void quant2t_kernel(const float* __restrict__ x,
                               unsigned char* __restrict__ qt,
                               const unsigned* __restrict__ amax_bits) {
  float s = load_scale(amax_bits);
  __shared__ unsigned char tile[64][68];
  int tj = blockIdx.x & 63;   // N tile (2 chunks of 32)
  int ti = blockIdx.x >> 6;   // K tile
  int t = threadIdx.x;
  int c = t & 63;
  int r0 = (t >> 6) * 16;
#pragma unroll
  for (int rr = 0; rr < 16; ++rr) {
    int r = r0 + rr;
    float v = x[(size_t)(ti * 64 + r) * N_DIM + tj * 64 + c];
    tile[c][r] = (unsigned char)f2fp8(v / s);  // tile[n][k]
  }
  __syncthreads();
  int n = t >> 2;             // 0..63
  int kc = (t & 3) << 4;      // 0,16,32,48
  const unsigned* lp = (const unsigned*)&tile[n][kc];
  uint4 v; v.x = lp[0]; v.y = lp[1]; v.z = lp[2]; v.w = lp[3];
  int n32 = tj * 2 + (n >> 5);
  size_t dst = ((size_t)n32 * 64 + ti) * 2048 +
               (size_t)(((kc >> 5) * 32 + (n & 31)) * 32 + (kc & 31));
  *(uint4*)&qt[dst] = v;
}

// ------------------------------------------------------------------ GEMM ----
// ZERO-LDS, ZERO-BARRIER register-streaming GEMM.
// 256x256 tile, 8 waves (2Mx4N), wave owns 128x64. Both operands are
// fragment-blocked in ws (chunk = 2048B = one wave-fragment; lane*32 + 2
// dwordx4). Per tile per wave: 12 loads + 8 MFMA_SC(32x32x64, scale=1.0
// exact). One-tile-ahead prefetch via static unroll-2 role swap. All waits
// are compiler-inserted per-register vmcnt; no inter-wave sync exists.
// L1 reuse: the 4 waves sharing wm read identical A chunks (L1 hits);
// unique L2 traffic 32KB/tile/CU ~ 29 B/cyc < ~60 ceiling -> MFMA-bound.
// XCD supertile map (kept from R10: FETCH 295->197MB): xcd owns 4col x 32row.
#define MFMA_SC(a, b, c)                                             \
  __builtin_amdgcn_mfma_scale_f32_32x32x64_f8f6f4(a, b, c, 0, 0, 0, 127, 0, 127)

__global__ __launch_bounds__(512, 2)
void gemm_fp8_kernel(const unsigned char* __restrict__ Aq,
                     const unsigned char* __restrict__ Bq,
                     float* __restrict__ C,
                     const unsigned* __restrict__ amax_bits) {
  int bid = blockIdx.x;
  int xcd = bid & 7;
  int j = bid >> 3;                                // 0..127
  int brow = ((xcd >> 2) * 32 + (j >> 2)) * 256;   // 64 row tiles
  int bcol = ((xcd & 3) * 4 + (j & 3)) * 256;      // 16 col tiles

  int t = threadIdx.x;
  int lane = t & 63, wid = t >> 6;
  int wm = wid >> 2, wn = wid & 3;                 // 2M x 4N
  int r5 = lane & 31;
  int khalf = lane >> 5;

  // A: groups pg = brow/32 + wm*4 + m, chunk(pg,k64) at (pg*64+k64)*2048
  const unsigned char* pA =
      Aq + ((size_t)((brow >> 5) + wm * 4) * 64) * 2048 + (size_t)lane * 32;
  // B: groups n32 = bcol/32 + wn*2 + n
  const unsigned char* pB =
      Bq + ((size_t)((bcol >> 5) + wn * 2) * 64) * 2048 + (size_t)lane * 32;

  auto LD = [&](const unsigned char* p) -> v8i {
    const v4i* q = (const v4i*)p;
    v4i lo = q[0], hi = q[1];
    return __builtin_shufflevector(lo, hi, 0, 1, 2, 3, 4, 5, 6, 7);
  };

  v16f acc[4][2] = {};
  v8i a[4], an[4], b[2], bn[2];

  // tile 0 into cur regs
#pragma unroll
  for (int m = 0; m < 4; ++m) a[m] = LD(pA + (size_t)m * 131072);
#pragma unroll
  for (int n = 0; n < 2; ++n) b[n] = LD(pB + (size_t)n * 131072);

#pragma unroll 1
  for (int T = 0; T < NT; T += 2) {
    // prefetch T+1 into nxt (T+1 <= 63 always)
#pragma unroll
    for (int m = 0; m < 4; ++m)
      an[m] = LD(pA + (size_t)m * 131072 + (size_t)(T + 1) * 2048);
#pragma unroll
    for (int n = 0; n < 2; ++n)
      bn[n] = LD(pB + (size_t)n * 131072 + (size_t)(T + 1) * 2048);

#pragma unroll
    for (int m = 0; m < 4; ++m) {
      acc[m][0] = MFMA_SC(a[m], b[0], acc[m][0]);
      acc[m][1] = MFMA_SC(a[m], b[1], acc[m][1]);
    }

    if (T + 2 < NT) {
#pragma unroll
      for (int m = 0; m < 4; ++m)
        a[m] = LD(pA + (size_t)m * 131072 + (size_t)(T + 2) * 2048);
#pragma unroll
      for (int n = 0; n < 2; ++n)
        b[n] = LD(pB + (size_t)n * 131072 + (size_t)(T + 2) * 2048);
    }

#pragma unroll
    for (int m = 0; m < 4; ++m) {
      acc[m][0] = MFMA_SC(an[m], bn[0], acc[m][0]);
      acc[m][1] = MFMA_SC(an[m], bn[1], acc[m][1]);
    }
  }

  // epilogue: 32x32 C/D map: col = lane&31, row = (reg&3)+8*(reg>>2)+4*(lane>>5)
  float scale = load_scale(amax_bits) * load_scale(amax_bits + 1);
  float* Cp = C + (size_t)(brow + wm * 128 + khalf * 4) * N_DIM +
              (bcol + wn * 64 + r5);
#pragma unroll
  for (int m = 0; m < 4; ++m)
#pragma unroll
    for (int r = 0; r < 16; ++r) {
      size_t ro = (size_t)(m * 32 + (r & 3) + 8 * (r >> 2)) * N_DIM;
#pragma unroll
      for (int n = 0; n < 2; ++n)
        Cp[ro + n * 32] = acc[m][n][r] * scale;
    }
}

// ----------------------------------------------------------------- launch ---
extern "C" void kernel_launch(void* const* d_in, const int* in_sizes, int n_in,
                              void* d_out, int out_size, void* d_ws,
                              size_t ws_size, hipStream_t stream) {
  const float* in1 = (const float*)d_in[0];
  const float* in2 = (const float*)d_in[1];
  float* out = (float*)d_out;
  unsigned char* ws = (unsigned char*)d_ws;

  const int R = in_sizes[0] / K_DIM;  // 16384
  const size_t qa_bytes = (size_t)R * K_DIM;
  const size_t qb_bytes = (size_t)N_DIM * K_DIM;
  const size_t need = 256 + qa_bytes + qb_bytes;
  if (ws_size < need) {
    fprintf(stderr, "kernel_launch: ws_size %zu < needed %zu\n", ws_size, need);
    return;
  }
  unsigned* amax = (unsigned*)ws;
  unsigned char* q1 = ws + 256;
  unsigned char* q2t = q1 + qa_bytes;

  hipMemsetAsync(ws, 0, 8, stream);
  amax_kernel<<<2048, 256, 0, stream>>>((const float4*)in1, in_sizes[0] / 4, amax);
  amax_kernel<<<1024, 256, 0, stream>>>((const float4*)in2, in_sizes[1] / 4, amax + 1);
  // one thread per 32B of Aq: R*K/32 threads
  quant1_kernel<<<(int)(qa_bytes / 32 / 256), 256, 0, stream>>>(in1, q1, amax);
  quant2t_kernel<<<(K_DIM / 64) * (N_DIM / 64), 256, 0, stream>>>(in2, q2t, amax + 1);
  gemm_fp8_kernel<<<(R / 256) * (N_DIM / 256), 512, 0, stream>>>(q1, q2t, out, amax);
}